// Round 8
// baseline (222.907 us; speedup 1.0000x reference)
//
#include <hip/hip_runtime.h>

// RouterAttention on gfx950. B=4 L=S=4096 D=512 H=8 E=R=64.
// R8: launch fusion 6 -> 4. One prep_k (canon X + rope tabs + zero + W
// transposes + Wqr/Wkr + bias), with per-block local dtype-flag computation
// (no sniff kernel, no cross-block dep). Weights read raw with flag branch.
// big_k / router_v / final_attn unchanged from R7.

#define DEV __device__ __forceinline__

constexpr int Bn = 4, Ln = 4096, Dn = 512, Hn = 8, En = 64, Rn = 64;
constexpr int Sn = 4096;
constexpr float SCALE = 0.125f;                 // 1/sqrt(E)
constexpr float L2B_OVER_K = 13.287712379549449f / 32.0f; // log2(10000)/32

typedef __bf16 bf16x8 __attribute__((ext_vector_type(8)));
typedef float floatx4 __attribute__((ext_vector_type(4)));

DEV float bf2f(ushort u) { return __uint_as_float(((unsigned)u) << 16); }
DEV ushort f2bf(float f) {
    unsigned u = __float_as_uint(f);
    u += 0x7fffu + ((u >> 16) & 1u);            // RNE
    return (ushort)(u >> 16);
}
DEV bf16x8 ldsfrag(const ushort* p) { return *reinterpret_cast<const bf16x8*>(p); }
#define MFMA(a, b, c) __builtin_amdgcn_mfma_f32_16x16x32_bf16(a, b, c, 0, 0, 0)

DEV void gload16(const ushort* g, ushort* lds) {
    __builtin_amdgcn_global_load_lds(
        (const __attribute__((address_space(1))) unsigned int*)g,
        (__attribute__((address_space(3))) unsigned int*)lds, 16, 0, 0);
}

DEV int wave_sum_i(int v) {
    #pragma unroll
    for (int off = 1; off < 64; off <<= 1) v += __shfl_xor(v, off);
    return v;
}

// raw-input readers (flag: 1 = f32 source, 0 = bf16 source)
DEV float ldf(const void* p, size_t i, int f) {
    return f ? ((const float*)p)[i] : bf2f(((const ushort*)p)[i]);
}
DEV ushort ldbf(const void* p, size_t i, int f) {
    return f ? f2bf(((const float*)p)[i]) : ((const ushort*)p)[i];
}
DEV void read8(const void* p, size_t off, int f, ushort* o8) {
    if (f) {
        float4 a = *((const float4*)((const float*)p + off));
        float4 b = *((const float4*)((const float*)p + off) + 1);
        o8[0] = f2bf(a.x); o8[1] = f2bf(a.y); o8[2] = f2bf(a.z); o8[3] = f2bf(a.w);
        o8[4] = f2bf(b.x); o8[5] = f2bf(b.y); o8[6] = f2bf(b.z); o8[7] = f2bf(b.w);
    } else {
        *(uint4*)o8 = *(const uint4*)((const ushort*)p + off);
    }
}

// ---- one mega prep kernel ----
// blocks: [0,4096) canon X | [4096,4608) rope tabs | [4608,4739) zero rV/lsum
//         [4739,4867) W transposes | [4867,4995) prep_wr | 4995 bias+flag
__global__ __launch_bounds__(256)
void prep_k(const void* xr, const void* Wqr_, const void* bqr, const void* Wkr_,
            const void* Wskr, const void* bskr, const void* Wzr, const void* bzr,
            const void* RPr, ushort* __restrict__ Xc, float2* __restrict__ tab_pj,
            float2* __restrict__ tab_jp, float* __restrict__ rV,
            float* __restrict__ lsum, ushort* __restrict__ Wtcat,
            ushort* __restrict__ Wkr, float* __restrict__ biascat,
            int* __restrict__ flagout) {
    __shared__ int redf[4];
    __shared__ ushort t64[64][65];
    __shared__ ushort As1[64][72];
    __shared__ ushort Bs1[64][72];
    const int bid = blockIdx.x, tid = threadIdx.x;
    // local dtype flag (deterministic, same in every block)
    {
        const uint* xw = (const uint*)xr;
        int cnt = 0;
        #pragma unroll
        for (int i = 0; i < 16; ++i) {
            uint u = xw[tid * 16 + i];
            uint e = (u >> 7) & 0xFF;
            cnt += (e >= 100 && e <= 140) ? 1 : 0;
        }
        cnt = wave_sum_i(cnt);
        if ((tid & 63) == 0) redf[tid >> 6] = cnt;
    }
    __syncthreads();
    const int f = ((redf[0] + redf[1] + redf[2] + redf[3]) < 2048) ? 1 : 0;

    if (bid < 4096) {                           // canon X: 8 elems/thread
        size_t i = ((size_t)bid * 256 + tid) * 8;
        ushort o8[8];
        read8(xr, i, f, o8);
        *(uint4*)&Xc[i] = *(uint4*)o8;
    } else if (bid < 4608) {                    // rope tables (both layouts)
        int idx = (bid - 4096) * 256 + tid;     // 131072 entries
        int p = idx >> 5, j = idx & 31;
        float theta = exp2f(-(float)j * L2B_OVER_K);
        float ang = (float)(Sn - 1 - p) * theta;
        float s, c;
        sincosf(ang, &s, &c);
        tab_pj[idx] = make_float2(c, s);
        tab_jp[j * Sn + p] = make_float2(c, s);
    } else if (bid < 4739) {                    // zero rV + lsum
        int base = (bid - 4608) * 1024 + tid;
        #pragma unroll
        for (int r = 0; r < 4; ++r) {
            int f32i = base + r * 256;
            if (f32i < 131072) rV[f32i] = 0.f;
            else if (f32i < 133120) lsum[f32i - 131072] = 0.f;
        }
    } else if (bid < 4867) {                    // transpose Wskip / Wz
        int idx = bid - 4739;
        const void* W = (idx < 64) ? Wskr : Wzr;
        ushort* Wt = Wtcat + (idx < 64 ? 0 : 262144);
        int bb = idx & 63;
        int bx = (bb & 7) * 64, by = (bb >> 3) * 64;
        int c = tid & 63, r0 = (tid >> 6) * 16;
        #pragma unroll
        for (int i = 0; i < 16; ++i)
            t64[r0 + i][c] = ldbf(W, (size_t)(by + r0 + i) * Dn + bx + c, f);
        __syncthreads();
        #pragma unroll
        for (int i = 0; i < 16; ++i)
            Wt[(size_t)(bx + r0 + i) * Dn + by + c] = t64[c][r0 + i];
    } else if (bid < 4995) {                    // prep_wr: Wqr (sec2) / Wkr
        int idx = bid - 4867;
        int zsel = idx >> 6, rem = idx & 63;
        int d0 = (rem & 7) * 64, h = rem >> 3;
        const void* W = zsel ? Wkr_ : Wqr_;
        ushort* Out = zsel ? Wkr : (Wtcat + 524288);
        #pragma unroll
        for (int j = 0; j < 2; ++j) {
            int lin = j * 256 + tid, row = lin >> 3, c = (lin & 7) * 8;
            read8(RPr, (size_t)row * Dn + h * En + c, f, &As1[row][c]);
            read8(W, (size_t)(d0 + row) * Dn + h * En + c, f, &Bs1[row][c]);
        }
        __syncthreads();
        const int w = tid >> 6, l = tid & 63;
        const int mt = (w >> 1) * 32, nt = (w & 1) * 32, lr = l & 15, lq = l >> 4;
        floatx4 acc[2][2] = {};
        #pragma unroll
        for (int ks = 0; ks < 64; ks += 32) {
            bf16x8 a0 = ldsfrag(&As1[mt + lr][ks + lq * 8]);
            bf16x8 a1 = ldsfrag(&As1[mt + 16 + lr][ks + lq * 8]);
            bf16x8 b0 = ldsfrag(&Bs1[nt + lr][ks + lq * 8]);
            bf16x8 b1 = ldsfrag(&Bs1[nt + 16 + lr][ks + lq * 8]);
            acc[0][0] = MFMA(a0, b0, acc[0][0]);
            acc[0][1] = MFMA(a0, b1, acc[0][1]);
            acc[1][0] = MFMA(a1, b0, acc[1][0]);
            acc[1][1] = MFMA(a1, b1, acc[1][1]);
        }
        #pragma unroll
        for (int mi = 0; mi < 2; ++mi)
            #pragma unroll
            for (int ni = 0; ni < 2; ++ni)
                #pragma unroll
                for (int ri = 0; ri < 4; ++ri) {
                    int ro = mt + mi * 16 + lq * 4 + ri;
                    int d = d0 + nt + ni * 16 + lr;
                    Out[(size_t)(h * En + ro) * Dn + d] = f2bf(acc[mi][ni][ri] * SCALE);
                }
    } else {                                    // bias + persist flag
        #pragma unroll
        for (int it = 0; it < 2; ++it) {
            int i = it * 256 + tid;
            biascat[i]       = ldf(bskr, i, f);
            biascat[512 + i] = ldf(bzr, i, f);
            int h = i >> 6, ro = i & 63;
            float s = 0.f;
            for (int e = 0; e < 64; ++e)
                s += ldf(bqr, h * En + e, f) * ldf(RPr, (size_t)ro * Dn + h * En + e, f);
            biascat[1024 + i] = s * SCALE;
        }
        if (tid == 0) flagout[0] = f;
    }
}

// ---- shared 128x128x512 K-loop, conflict-free swizzle ----
DEV void kloop128(const ushort* __restrict__ Ag, const ushort* __restrict__ Bg,
                  int m0, int n0, ushort* As, ushort* Bs, int tid,
                  floatx4 (&acc)[4][4]) {
    const int w = tid >> 6, l = tid & 63;
    const int mt = (w >> 1) * 64, nt = (w & 1) * 64;
    const int lr = l & 15, lq = l >> 4;
    for (int kc = 0; kc < Dn; kc += 64) {
        __syncthreads();
        #pragma unroll
        for (int j = 0; j < 4; ++j) {
            int slot = (w * 4 + j) * 64 + l;
            int row = slot >> 3;
            int c = ((slot & 7) - row) & 7;
            gload16(&Ag[(size_t)(m0 + row) * Dn + kc + c * 8], &As[(w * 4 + j) * 512]);
            gload16(&Bg[(size_t)(n0 + row) * Dn + kc + c * 8], &Bs[(w * 4 + j) * 512]);
        }
        __syncthreads();
        #pragma unroll
        for (int ks = 0; ks < 64; ks += 32) {
            bf16x8 a[4], bb[4];
            const int cc = (ks >> 3) + lq;
            #pragma unroll
            for (int i = 0; i < 4; ++i) {
                int row = mt + 16 * i + lr;
                a[i] = ldsfrag(&As[(row * 8 + ((cc + row) & 7)) * 8]);
            }
            #pragma unroll
            for (int i = 0; i < 4; ++i) {
                int row = nt + 16 * i + lr;
                bb[i] = ldsfrag(&Bs[(row * 8 + ((cc + row) & 7)) * 8]);
            }
            #pragma unroll
            for (int mi = 0; mi < 4; ++mi)
                #pragma unroll
                for (int ni = 0; ni < 4; ++ni)
                    acc[mi][ni] = MFMA(a[mi], bb[ni], acc[mi][ni]);
        }
    }
}

// ---- big_k: gemm_fused (1536 blocks) || rscore_gemm (512 blocks), 3:1 ----
__global__ __launch_bounds__(256)
void big_k(const ushort* __restrict__ X, const ushort* __restrict__ Wtcat,
           const float* __restrict__ biascat, const ushort* __restrict__ Wkr,
           ushort* __restrict__ skip, ushort* __restrict__ z,
           ushort* __restrict__ qs, ushort* __restrict__ E,
           float* __restrict__ lsum) {
    __shared__ __align__(16) ushort As[8192];
    __shared__ __align__(16) ushort Bs[8192];
    const int bid = blockIdx.x, tid = threadIdx.x;
    const int w = tid >> 6, l = tid & 63;
    const int mt = (w >> 1) * 64, nt = (w & 1) * 64;
    const int lr = l & 15, lq = l >> 4;
    floatx4 acc[4][4] = {};
    if ((bid & 3) != 3) {                       // ---- projection GEMM ----
        int idx = (bid >> 2) * 3 + (bid & 3);   // 0..1535
        const int n0 = (idx % 12) * 128;
        const int m0 = (idx / 12) * 128;
        kloop128(X, Wtcat, m0, n0, As, Bs, tid, acc);
        const int sec = n0 >> 9;                // 0=skip 1=z 2=qs
        ushort* dst = sec == 0 ? skip : (sec == 1 ? z : qs);
        #pragma unroll
        for (int ni = 0; ni < 4; ++ni) {
            int ng = n0 + nt + ni * 16 + lr;
            float bbv = biascat[ng];
            int nc = ng & 511;
            #pragma unroll
            for (int mi = 0; mi < 4; ++mi)
                #pragma unroll
                for (int ri = 0; ri < 4; ++ri) {
                    int row = m0 + mt + mi * 16 + lq * 4 + ri;
                    float v = acc[mi][ni][ri] + bbv;
                    if (sec == 1) v = v / (1.0f + __expf(-v));
                    dst[(size_t)row * Dn + nc] = f2bf(v);
                }
        }
    } else {                                    // ---- router scores GEMM ----
        int idx = bid >> 2;                     // 0..511
        const int n0 = (idx & 127) * 128;       // x row = b*4096+s
        const int m0 = (idx >> 7) * 128;        // Wkr row = h*64+r
        kloop128(Wkr, X, m0, n0, As, Bs, tid, acc);
        const int b = n0 >> 12;
        const int sbase = (n0 & 4095) + nt;
        #pragma unroll
        for (int mi = 0; mi < 4; ++mi)
            #pragma unroll
            for (int ri = 0; ri < 4; ++ri) {
                size_t row = (size_t)(b * 512 + m0 + mt + mi * 16 + lq * 4 + ri);
                float rs = 0.f;
                #pragma unroll
                for (int ni = 0; ni < 4; ++ni) {
                    int s = sbase + ni * 16 + lr;
                    float e = __expf(acc[mi][ni][ri]);
                    E[row * Sn + s] = f2bf(e);
                    rs += e;
                }
                rs += __shfl_xor(rs, 1); rs += __shfl_xor(rs, 2);
                rs += __shfl_xor(rs, 4); rs += __shfl_xor(rs, 8);
                if (lr == 0) atomicAdd(&lsum[row], rs);
            }
    }
}

// ---- rV[bh][r][e] += sum_s rope(E/l)[r][s] * v[s][e]; K=128 single-stage ----
__global__ __launch_bounds__(256)
void router_v_k(const ushort* __restrict__ E, const float* __restrict__ lsum,
                const ushort* __restrict__ X, const float2* __restrict__ tab_jp,
                float* __restrict__ rV) {
    __shared__ ushort As[64][136];   // rope(E/l)[r][s0..127]
    __shared__ ushort Bs[64][136];   // v^T[e][s]
    __shared__ float invl[64];
    const int tid = threadIdx.x;
    const int bh = blockIdx.y, b = bh >> 3, h = bh & 7;
    const int sb = blockIdx.x * 128;
    if (tid < 64) invl[tid] = 1.0f / lsum[(size_t)bh * Rn + tid];
    __syncthreads();
    #pragma unroll
    for (int it = 0; it < 16; ++it) {           // rope staging: (j, s)
        int lin = it * 256 + tid;
        int j = lin >> 7, sl = lin & 127;
        int sg = sb + sl;
        float pe = bf2f(E[((size_t)bh * Rn + 2 * j) * Sn + sg]) * invl[2 * j];
        float po = bf2f(E[((size_t)bh * Rn + 2 * j + 1) * Sn + sg]) * invl[2 * j + 1];
        float2 cs = tab_jp[j * Sn + sg];        // coalesced in s
        As[2 * j][sl]     = f2bf(pe * cs.x - po * cs.y);
        As[2 * j + 1][sl] = f2bf(pe * cs.y + po * cs.x);
    }
    #pragma unroll
    for (int it = 0; it < 4; ++it) {            // v^T staging, uint4 loads
        int lin = it * 256 + tid;
        int s = lin >> 3, eg = (lin & 7) * 8;
        ushort u8[8];
        *(uint4*)u8 = *(const uint4*)&X[(size_t)(b * Ln + sb + s) * Dn + h * En + eg];
        #pragma unroll
        for (int t = 0; t < 8; ++t) Bs[eg + t][s] = u8[t];
    }
    __syncthreads();
    const int w = tid >> 6, l = tid & 63;
    const int mt = (w >> 1) * 32, nt = (w & 1) * 32, lr = l & 15, lq = l >> 4;
    floatx4 acc[2][2] = {};
    #pragma unroll
    for (int ks = 0; ks < 128; ks += 32) {
        bf16x8 a0 = ldsfrag(&As[mt + lr][ks + lq * 8]);
        bf16x8 a1 = ldsfrag(&As[mt + 16 + lr][ks + lq * 8]);
        bf16x8 b0 = ldsfrag(&Bs[nt + lr][ks + lq * 8]);
        bf16x8 b1 = ldsfrag(&Bs[nt + 16 + lr][ks + lq * 8]);
        acc[0][0] = MFMA(a0, b0, acc[0][0]);
        acc[0][1] = MFMA(a0, b1, acc[0][1]);
        acc[1][0] = MFMA(a1, b0, acc[1][0]);
        acc[1][1] = MFMA(a1, b1, acc[1][1]);
    }
    #pragma unroll
    for (int mi = 0; mi < 2; ++mi)
        #pragma unroll
        for (int ni = 0; ni < 2; ++ni)
            #pragma unroll
            for (int ri = 0; ri < 4; ++ri) {
                int r = mt + mi * 16 + lq * 4 + ri;
                int e = nt + ni * 16 + lr;
                atomicAdd(&rV[((size_t)bh * Rn + r) * En + e], acc[mi][ni][ri]);
            }
}

// ---- fused query path: qs -> in-thread softmax -> rope -> @rV -> (+skip)*z ----
__global__ __launch_bounds__(256)
void final_attn_k(const ushort* __restrict__ QS, const float* __restrict__ rV,
                  const float2* __restrict__ tab_pj, const ushort* __restrict__ Skip,
                  const ushort* __restrict__ Zs, const int* __restrict__ flagp,
                  void* __restrict__ Outv) {
    __shared__ ushort Ap[64][72];
    __shared__ ushort BvT[64][72];
    __shared__ float Cs[64][68];
    const int f = *flagp;
    const int tid = threadIdx.x;
    const int h = blockIdx.y, b = blockIdx.z, bh = b * Hn + h;
    const int l0 = blockIdx.x * 64;
    const int w = tid >> 6, l = tid & 63;
    const int mt = (w >> 1) * 32, nt = (w & 1) * 32, lr = l & 15, lq = l >> 4;
    #pragma unroll
    for (int i = 0; i < 16; ++i) {
        int lin = i * 256 + tid, r = lin >> 6, e = lin & 63;
        BvT[e][r] = f2bf(rV[((size_t)bh * Rn + r) * En + e]);
    }
    {   // quad-per-token softmax + rope
        const int lt = tid >> 2, qd = tid & 3;
        const ushort* qrow = &QS[(size_t)(b * Ln + l0 + lt) * Dn + h * En + qd * 16];
        uint4 u0 = ((const uint4*)qrow)[0];
        uint4 u1 = ((const uint4*)qrow)[1];
        uint uw[8] = {u0.x, u0.y, u0.z, u0.w, u1.x, u1.y, u1.z, u1.w};
        float p[16];
        float s = 0.f;
        #pragma unroll
        for (int j = 0; j < 8; ++j) {
            float flo = __uint_as_float(uw[j] << 16);
            float fhi = __uint_as_float(uw[j] & 0xffff0000u);
            float e0 = __expf(flo), e1 = __expf(fhi);
            p[2 * j] = e0; p[2 * j + 1] = e1;
            s += e0 + e1;
        }
        s += __shfl_xor(s, 1);
        s += __shfl_xor(s, 2);
        float inv = 1.0f / s;
        #pragma unroll
        for (int u = 0; u < 8; ++u) {
            float A0 = p[2 * u] * inv, A1 = p[2 * u + 1] * inv;
            float2 cs = tab_pj[(l0 + lt) * 32 + qd * 8 + u];
            Ap[lt][qd * 16 + 2 * u]     = f2bf(A0 * cs.x - A1 * cs.y);
            Ap[lt][qd * 16 + 2 * u + 1] = f2bf(A0 * cs.y + A1 * cs.x);
        }
    }
    __syncthreads();
    floatx4 acc[2][2] = {};
    #pragma unroll
    for (int ks = 0; ks < 64; ks += 32) {
        bf16x8 a0 = ldsfrag(&Ap[mt + lr][ks + lq * 8]);
        bf16x8 a1 = ldsfrag(&Ap[mt + 16 + lr][ks + lq * 8]);
        bf16x8 b0 = ldsfrag(&BvT[nt + lr][ks + lq * 8]);
        bf16x8 b1 = ldsfrag(&BvT[nt + 16 + lr][ks + lq * 8]);
        acc[0][0] = MFMA(a0, b0, acc[0][0]);
        acc[0][1] = MFMA(a0, b1, acc[0][1]);
        acc[1][0] = MFMA(a1, b0, acc[1][0]);
        acc[1][1] = MFMA(a1, b1, acc[1][1]);
    }
    #pragma unroll
    for (int mi = 0; mi < 2; ++mi)
        #pragma unroll
        for (int ni = 0; ni < 2; ++ni)
            #pragma unroll
            for (int ri = 0; ri < 4; ++ri)
                Cs[mt + mi * 16 + lq * 4 + ri][nt + ni * 16 + lr] = acc[mi][ni][ri];
    __syncthreads();
    {   // vectorized epilogue: thread = (token, 16-e group)
        const int token = tid >> 2, e0 = (tid & 3) * 16;
        size_t base = (size_t)(b * Ln + l0 + token) * Dn + h * En + e0;
        uint4 sk0 = *(const uint4*)&Skip[base];
        uint4 sk1 = *(const uint4*)&Skip[base + 8];
        uint4 zz0 = *(const uint4*)&Zs[base];
        uint4 zz1 = *(const uint4*)&Zs[base + 8];
        uint sks[8] = {sk0.x, sk0.y, sk0.z, sk0.w, sk1.x, sk1.y, sk1.z, sk1.w};
        uint zzs[8] = {zz0.x, zz0.y, zz0.z, zz0.w, zz1.x, zz1.y, zz1.z, zz1.w};
        float ov[16];
        #pragma unroll
        for (int j = 0; j < 8; ++j) {
            float s0 = __uint_as_float(sks[j] << 16);
            float s1 = __uint_as_float(sks[j] & 0xffff0000u);
            float z0 = __uint_as_float(zzs[j] << 16);
            float z1 = __uint_as_float(zzs[j] & 0xffff0000u);
            ov[2 * j]     = (Cs[token][e0 + 2 * j] + s0) * z0;
            ov[2 * j + 1] = (Cs[token][e0 + 2 * j + 1] + s1) * z1;
        }
        if (f) {
            float* op = (float*)Outv + base;
            #pragma unroll
            for (int q = 0; q < 4; ++q)
                *(float4*)(op + 4 * q) = make_float4(ov[4 * q], ov[4 * q + 1],
                                                     ov[4 * q + 2], ov[4 * q + 3]);
        } else {
            ushort o16[16];
            #pragma unroll
            for (int t = 0; t < 16; ++t) o16[t] = f2bf(ov[t]);
            *(uint4*)((ushort*)Outv + base)     = *(uint4*)o16;
            *(uint4*)((ushort*)Outv + base + 8) = *(uint4*)(o16 + 8);
        }
    }
}

extern "C" void kernel_launch(void* const* d_in, const int* in_sizes, int n_in,
                              void* d_out, int out_size, void* d_ws, size_t ws_size,
                              hipStream_t stream) {
    const size_t OFF_SK    = 0;                  // 16 MiB bf16 [16384][512]
    const size_t OFF_Z     = 16777216;
    const size_t OFF_QS    = 33554432;
    const size_t OFF_E     = 50331648;           // 16 MiB bf16 E
    const size_t OFF_RV    = 67108864;           // 512 KiB f32
    const size_t OFF_L     = 67633152;           // 8 KiB f32 lsum
    const size_t OFF_TAB   = 67641344;           // 1 MiB tab_pj
    const size_t OFF_TABJP = 68689920;           // 1 MiB tab_jp
    const size_t OFF_WT    = 69738496;           // Wtcat 1536x512 bf16 = 1.5 MiB
    const size_t OFF_WKR   = 71311360;           // 512x512 bf16
    const size_t OFF_BIAS  = 71835648;           // 1536 f32
    const size_t OFF_XC    = 71841792;           // X bf16 16 MiB
    const size_t OFF_FLAG  = OFF_XC + 16777216;
    const size_t NEED      = OFF_FLAG + 16;      // ~88.6 MB
    if (ws_size < NEED) return;

    char* ws = (char*)d_ws;
    ushort* skip  = (ushort*)(ws + OFF_SK);
    ushort* z     = (ushort*)(ws + OFF_Z);
    ushort* qs    = (ushort*)(ws + OFF_QS);
    ushort* E     = (ushort*)(ws + OFF_E);
    float*  rV    = (float*)(ws + OFF_RV);
    float*  lsum  = (float*)(ws + OFF_L);
    float2* tabpj = (float2*)(ws + OFF_TAB);
    float2* tabjp = (float2*)(ws + OFF_TABJP);
    ushort* Wtcat = (ushort*)(ws + OFF_WT);
    ushort* Wkr   = (ushort*)(ws + OFF_WKR);
    float*  bias  = (float*)(ws + OFF_BIAS);
    ushort* Xc    = (ushort*)(ws + OFF_XC);
    int*    flag  = (int*)(ws + OFF_FLAG);

    prep_k<<<4996, 256, 0, stream>>>(d_in[0], d_in[1], d_in[2], d_in[3], d_in[5],
                                     d_in[6], d_in[7], d_in[8], d_in[9],
                                     Xc, tabpj, tabjp, rV, lsum, Wtcat, Wkr,
                                     bias, flag);
    big_k<<<2048, 256, 0, stream>>>(Xc, Wtcat, bias, Wkr, skip, z, qs, E, lsum);
    router_v_k<<<dim3(32, 32), 256, 0, stream>>>(E, lsum, Xc, tabjp, rV);
    final_attn_k<<<dim3(64, 8, 4), 256, 0, stream>>>(qs, rV, tabpj, skip, z, flag, d_out);
}